// Round 22
// baseline (483.758 us; speedup 1.0000x reference)
//
#include <hip/hip_runtime.h>
#include <math.h>

#define VSZ   30522
#define DIM   768
#define KDELT 768
#define BOT   512
#define BATCH 256
#define MNEG  4096
#define EPSN  1e-6f
#define TEMPC 0.05f
#define INVT  20.0f
#define TKT   1024
#define CCAP  2048

typedef _Float16 f16;
typedef _Float16 f16x8 __attribute__((ext_vector_type(8)));
typedef _Float16 f16x2 __attribute__((ext_vector_type(2)));
typedef float    f32x4 __attribute__((ext_vector_type(4)));

static __device__ __forceinline__ float gelu_exact(float x){
    return 0.5f * x * (1.0f + erff(x * 0.70710678118654752440f));
}
static __device__ __forceinline__ float softplus_f(float x){
    return fmaxf(x, 0.0f) + log1pf(expf(-fabsf(x)));
}
static __device__ __forceinline__ f16x2 pkh(float a, float b){
    return __builtin_bit_cast(f16x2, __builtin_amdgcn_cvt_pkrtz(a, b));
}
// order-preserving map float -> uint (handles negatives)
static __device__ __forceinline__ unsigned int fkey(float f){
    const unsigned int u = __float_as_uint(f);
    return u ^ (((unsigned int)((int)u >> 31)) | 0x80000000u);
}

// ---------------------------------------------------------------------------
// fp32-in / fp16-MFMA GEMM, 128x128 tile + XCD swizzle. R21 change: MINIMAL
// 2-deep register prefetch — two named staging sets (A/B), ONE LDS buffer
// pair, barrier structure unchanged. Store of set X waits (via compiler
// dataflow vmcnt) only on X's loads, issued TWO steps earlier -> latency
// coverage ~2 compute phases instead of 1. R12's failed dbuf attempt was
// confounded (4 LDS buffers + restructured barriers); this isolates depth.
// ---------------------------------------------------------------------------
template<int BSRC, int NG, int EPI, int LDA, int LDB, int N, int K, int NSPLIT,
         int GX, int GY, int GZ>
__global__ __launch_bounds__(256, 2) void gemm32t(
    const float* __restrict__ A0, const float* __restrict__ A1,
    const float* __restrict__ B0, const float* __restrict__ B1,
    float* __restrict__ C0, float* __restrict__ C1,
    const float* __restrict__ bias0, const float* __restrict__ bias1)
{
    constexpr int MN = BATCH * N;
    __shared__ f16 Al[128][40];
    __shared__ f16 Bl[128][40];
    const int t  = threadIdx.x;

    // ---- XCD-aware bijective remap (hw dispatch slot -> work id) ----
    const int flat = blockIdx.x + GX * (blockIdx.y + GY * blockIdx.z);
    constexpr int NWG = GX * GY * GZ;
    constexpr int q8 = NWG / 8, r8 = NWG % 8;
    const int xcd = flat & 7;
    const int sub = flat >> 3;
    const int wg  = (xcd < r8) ? (xcd * (q8 + 1) + sub)
                               : (r8 * (q8 + 1) + (xcd - r8) * q8 + sub);
    const int bx = wg % GX;
    const int by = (wg / GX) % GY;
    const int bz = wg / (GX * GY);

    const int m0 = bx * 128;
    const int n0 = by * 128;
    const int br = bz / NSPLIT;
    const int s  = bz % NSPLIT;
    const float* __restrict__ A = br ? A1 : A0;
    const float* __restrict__ B = br ? B1 : B0;
    float* __restrict__ C       = br ? C1 : C0;
    const float* __restrict__ bias = br ? bias1 : bias0;

    constexpr int kchunk = ((K + NSPLIT * 32 - 1) / (NSPLIT * 32)) * 32;
    const int kb = s * kchunk;
    const int ke = min(K, kb + kchunk);

    const int ar4 = t >> 2;          // staging row 0..63 (two passes)
    const int kq  = (t & 3) * 8;     // k-octet base 0,8,16,24
    const int bn  = t & 127;         // B transpose staging n
    const int bk2 = (t >> 7) * 16;   // B staging k-half base 0/16

    const int lane = t & 63, w = t >> 6;
    const int wr = (w >> 1) * 64, wc = (w & 1) * 64;
    const int fr = lane & 15, kg = (lane >> 4) * 8;

    f32x4 acc[4][4] = {};

    // two named staging sets (2-deep prefetch)
    float4 raA[2][2], raB[2][2];
    float  rbA[16],   rbB[16];
    float4 rb2A[2][2], rb2B[2][2];

    union U8 { f16x8 v; f16x2 h[4]; };

    auto loadA = [&](int k0c, int krem, float4 (&ra)[2][2]) {
        #pragma unroll
        for (int p = 0; p < 2; p++) {
            const float* ap = A + (size_t)(m0 + p * 64 + ar4) * LDA + k0c + kq;
            if (krem == 32) {
                ra[p][0] = *(const float4*)ap;
                ra[p][1] = *(const float4*)(ap + 4);
            } else {
                float tm[8];
                #pragma unroll
                for (int i = 0; i < 8; i++) tm[i] = (kq + i < krem) ? ap[i] : 0.f;
                ra[p][0] = make_float4(tm[0], tm[1], tm[2], tm[3]);
                ra[p][1] = make_float4(tm[4], tm[5], tm[6], tm[7]);
            }
        }
    };
    auto loadB = [&](int k0c, int krem, float (&rb)[16], float4 (&rb2)[2][2]) {
        if (BSRC == 0) {
            const bool nok = (!NG) || (n0 + bn < N);
            if (krem == 32) {
                #pragma unroll
                for (int p = 0; p < 16; p++)
                    rb[p] = nok ? B[(size_t)(k0c + bk2 + p) * LDB + n0 + bn] : 0.f;
            } else {
                #pragma unroll
                for (int p = 0; p < 16; p++) {
                    const int kk = bk2 + p;
                    rb[p] = (kk < krem && nok) ? B[(size_t)(k0c + kk) * LDB + n0 + bn] : 0.f;
                }
            }
        } else {
            #pragma unroll
            for (int p = 0; p < 2; p++) {
                const float* bp = B + (size_t)(n0 + p * 64 + ar4) * LDB + k0c + kq;
                if (krem == 32) {
                    rb2[p][0] = *(const float4*)bp;
                    rb2[p][1] = *(const float4*)(bp + 4);
                } else {
                    float tm[8];
                    #pragma unroll
                    for (int i = 0; i < 8; i++) tm[i] = (kq + i < krem) ? bp[i] : 0.f;
                    rb2[p][0] = make_float4(tm[0], tm[1], tm[2], tm[3]);
                    rb2[p][1] = make_float4(tm[4], tm[5], tm[6], tm[7]);
                }
            }
        }
    };
    auto storeA = [&](const float4 (&ra)[2][2]) {
        #pragma unroll
        for (int p = 0; p < 2; p++) {
            U8 u;
            u.h[0] = pkh(ra[p][0].x, ra[p][0].y);
            u.h[1] = pkh(ra[p][0].z, ra[p][0].w);
            u.h[2] = pkh(ra[p][1].x, ra[p][1].y);
            u.h[3] = pkh(ra[p][1].z, ra[p][1].w);
            *(f16x8*)&Al[p * 64 + ar4][kq] = u.v;
        }
    };
    auto storeB = [&](const float (&rb)[16], const float4 (&rb2)[2][2]) {
        if (BSRC == 0) {
            U8 u0, u1;
            u0.h[0] = pkh(rb[0],  rb[1]);
            u0.h[1] = pkh(rb[2],  rb[3]);
            u0.h[2] = pkh(rb[4],  rb[5]);
            u0.h[3] = pkh(rb[6],  rb[7]);
            u1.h[0] = pkh(rb[8],  rb[9]);
            u1.h[1] = pkh(rb[10], rb[11]);
            u1.h[2] = pkh(rb[12], rb[13]);
            u1.h[3] = pkh(rb[14], rb[15]);
            *(f16x8*)&Bl[bn][bk2]     = u0.v;
            *(f16x8*)&Bl[bn][bk2 + 8] = u1.v;
        } else {
            #pragma unroll
            for (int p = 0; p < 2; p++) {
                U8 u;
                u.h[0] = pkh(rb2[p][0].x, rb2[p][0].y);
                u.h[1] = pkh(rb2[p][0].z, rb2[p][0].w);
                u.h[2] = pkh(rb2[p][1].x, rb2[p][1].y);
                u.h[3] = pkh(rb2[p][1].z, rb2[p][1].w);
                *(f16x8*)&Bl[p * 64 + ar4][kq] = u.v;
            }
        }
    };
    auto compute = [&]() {
        f16x8 af[4], bf[4];
        #pragma unroll
        for (int m = 0; m < 4; m++) af[m] = *(const f16x8*)&Al[wr + m * 16 + fr][kg];
        #pragma unroll
        for (int n = 0; n < 4; n++) bf[n] = *(const f16x8*)&Bl[wc + n * 16 + fr][kg];
        #pragma unroll
        for (int m = 0; m < 4; m++)
            #pragma unroll
            for (int n = 0; n < 4; n++)
                acc[m][n] = __builtin_amdgcn_mfma_f32_16x16x32_f16(af[m], bf[n], acc[m][n], 0, 0, 0);
    };

    // prologue: 2-deep register fill
    {
        const int kr = min(32, ke - kb);
        loadA(kb, kr, raA); loadB(kb, kr, rbA, rb2A);
    }
    if (kb + 32 < ke) {
        const int kr = min(32, ke - (kb + 32));
        loadA(kb + 32, kr, raB); loadB(kb + 32, kr, rbB, rb2B);
    }

    int kc = kb;
    for (;;) {
        // ---- phase A (set raA/rbA holds data for step kc)
        storeA(raA); storeB(rbA, rb2A);
        __syncthreads();
        {
            const int kn = kc + 64;
            if (kn < ke) { const int kr = min(32, ke - kn); loadA(kn, kr, raA); loadB(kn, kr, rbA, rb2A); }
        }
        compute();
        __syncthreads();
        kc += 32;
        if (kc >= ke) break;

        // ---- phase B (set raB/rbB holds data for step kc)
        storeA(raB); storeB(rbB, rb2B);
        __syncthreads();
        {
            const int kn = kc + 64;
            if (kn < ke) { const int kr = min(32, ke - kn); loadA(kn, kr, raB); loadB(kn, kr, rbB, rb2B); }
        }
        compute();
        __syncthreads();
        kc += 32;
        if (kc >= ke) break;
    }

    float* Cp = (EPI == 0) ? (C + (size_t)s * MN) : C;
    #pragma unroll
    for (int m = 0; m < 4; m++) {
        #pragma unroll
        for (int n = 0; n < 4; n++) {
            #pragma unroll
            for (int j = 0; j < 4; j++) {
                const int row = m0 + wr + m * 16 + (lane >> 4) * 4 + j;
                const int col = n0 + wc + n * 16 + fr;
                if (NG && col >= N) continue;
                if (EPI == 0) Cp[(size_t)row * N + col] = acc[m][n][j];
                else          Cp[(size_t)row * N + col] = acc[m][n][j] + bias[col];
            }
        }
    }
}

// dual-branch split-K reduce + bias + exact GELU
__global__ __launch_bounds__(256) void reduce_bias_gelu2(
    const float* __restrict__ P0, const float* __restrict__ P1,
    const float* __restrict__ bias0, const float* __restrict__ bias1,
    float* __restrict__ H0, float* __restrict__ H1,
    int MN, int N, int nsplit)
{
    const int idx = blockIdx.x * 256 + threadIdx.x;
    if (idx >= MN) return;
    const int n = idx % N;
    const float* P = blockIdx.y ? P1 : P0;
    const float* bias = blockIdx.y ? bias1 : bias0;
    float* H = blockIdx.y ? H1 : H0;
    float s = 0.f;
    for (int k = 0; k < nsplit; k++) s += P[(size_t)k * MN + idx];
    H[idx] = gelu_exact(s + bias[n]);
}

__global__ __launch_bounds__(256) void reduce_sum_parts(
    const float* __restrict__ P, float* __restrict__ Y, int MN, int nsplit)
{
    const int idx = blockIdx.x * 256 + threadIdx.x;
    if (idx >= MN) return;
    float s = 0.f;
    for (int k = 0; k < nsplit; k++) s += P[(size_t)k * MN + idx];
    Y[idx] = s;
}

// ---------------------------------------------------------------------------
// FUSED per-row kernel (R20 collect-select): pass A = 12-bit histogram +
// suffix scan -> boundary bin & rank; pass B = collect bin elements to LDS,
// value-count select (order-independent, exact); fallback full radix if
// bin > CCAP. Then build sq in place + sparse sums.
// ---------------------------------------------------------------------------
__global__ __launch_bounds__(TKT) void topk_build(
    float* __restrict__ U1, const float* __restrict__ U2,
    const float* __restrict__ sr,
    float* __restrict__ sparse_p, float* __restrict__ sparse_m)
{
    __shared__ unsigned int hist[4096];
    __shared__ unsigned int scan[TKT];
    __shared__ unsigned int cand[CCAP];
    __shared__ unsigned int s_pref;
    __shared__ int s_rem;
    __shared__ unsigned int s_cnt;
    __shared__ unsigned int s_thr;
    const int row = blockIdx.x, t = threadIdx.x;
    float* fred = (float*)hist;              // build-phase reduction (aliases hist)

    float th[2];
    #pragma unroll
    for (int b = 0; b < 2; b++) {
        const float* u = (b ? U2 : U1) + (size_t)row * VSZ;

        // ---- pass A: 12-bit histogram ----
        for (int i = t; i < 4096; i += TKT) hist[i] = 0;
        __syncthreads();
        for (int j = t; j < VSZ / 2; j += TKT) {
            const float2 x = *(const float2*)(u + 2 * j);
            atomicAdd(&hist[fkey(x.x) >> 20], 1u);
            atomicAdd(&hist[fkey(x.y) >> 20], 1u);
        }
        __syncthreads();
        // suffix scan: thread t owns bins [4t, 4t+4)
        unsigned int loc = hist[4 * t] + hist[4 * t + 1] + hist[4 * t + 2] + hist[4 * t + 3];
        scan[t] = loc;
        __syncthreads();
        for (int o = 1; o < TKT; o <<= 1) {
            const unsigned int v = (t + o < TKT) ? scan[t + o] : 0u;
            __syncthreads();
            scan[t] += v;
            __syncthreads();
        }
        const unsigned int above = (t + 1 < TKT) ? scan[t + 1] : 0u;
        if (scan[t] >= (unsigned int)KDELT && above < (unsigned int)KDELT) {
            unsigned int cum = above;
            #pragma unroll
            for (int bi = 3; bi >= 0; bi--) {
                const int bb = 4 * t + bi;
                cum += hist[bb];
                if (cum >= (unsigned int)KDELT) {
                    s_pref = (unsigned int)bb;
                    s_rem  = KDELT - (int)(cum - hist[bb]);
                    break;
                }
            }
        }
        __syncthreads();
        const unsigned int bin = s_pref;
        const int r = s_rem;
        const unsigned int bincnt = hist[bin];

        if (bincnt <= CCAP) {
            // ---- pass B: collect boundary-bin elements, value-count select
            if (t == 0) s_cnt = 0;
            __syncthreads();
            for (int j = t; j < VSZ / 2; j += TKT) {
                const float2 x = *(const float2*)(u + 2 * j);
                const unsigned int k0 = fkey(x.x);
                const unsigned int k1 = fkey(x.y);
                if ((k0 >> 20) == bin) cand[atomicAdd(&s_cnt, 1u)] = k0;
                if ((k1 >> 20) == bin) cand[atomicAdd(&s_cnt, 1u)] = k1;
            }
            __syncthreads();
            const int cnt = (int)s_cnt;
            for (int i = t; i < cnt; i += TKT) {
                const unsigned int ki = cand[i];
                int greater = 0, eq = 0;
                for (int j2 = 0; j2 < cnt; j2++) {
                    const unsigned int kj = cand[j2];
                    greater += (kj > ki);
                    eq      += (kj == ki);
                }
                if (greater < r && r <= greater + eq) s_thr = ki;
            }
            __syncthreads();
            const unsigned int pk = s_thr;
            th[b] = __uint_as_float((pk & 0x80000000u) ? (pk ^ 0x80000000u) : ~pk);
            __syncthreads();
        } else {
            // ---- fallback: original 12-bit then 8-bit refinement passes
            unsigned int pref = bin;
            int remain = r;
            #pragma unroll
            for (int p = 1; p < 3; p++) {
                for (int i = t; i < 4096; i += TKT) hist[i] = 0;
                __syncthreads();
                for (int j = t; j < VSZ / 2; j += TKT) {
                    const float2 x = *(const float2*)(u + 2 * j);
                    const unsigned int k0 = fkey(x.x);
                    const unsigned int k1 = fkey(x.y);
                    if (p == 1) {
                        if ((k0 >> 20) == pref) atomicAdd(&hist[(k0 >> 8) & 0xFFFu], 1u);
                        if ((k1 >> 20) == pref) atomicAdd(&hist[(k1 >> 8) & 0xFFFu], 1u);
                    } else {
                        if ((k0 >> 8) == pref) atomicAdd(&hist[k0 & 0xFFu], 1u);
                        if ((k1 >> 8) == pref) atomicAdd(&hist[k1 & 0xFFu], 1u);
                    }
                }
                __syncthreads();
                unsigned int loc2 = hist[4 * t] + hist[4 * t + 1] + hist[4 * t + 2] + hist[4 * t + 3];
                scan[t] = loc2;
                __syncthreads();
                for (int o = 1; o < TKT; o <<= 1) {
                    const unsigned int v = (t + o < TKT) ? scan[t + o] : 0u;
                    __syncthreads();
                    scan[t] += v;
                    __syncthreads();
                }
                const unsigned int abv = (t + 1 < TKT) ? scan[t + 1] : 0u;
                if (scan[t] >= (unsigned int)remain && abv < (unsigned int)remain) {
                    unsigned int cum = abv;
                    #pragma unroll
                    for (int bi = 3; bi >= 0; bi--) {
                        const int bb = 4 * t + bi;
                        cum += hist[bb];
                        if (cum >= (unsigned int)remain) {
                            s_pref = (unsigned int)bb;
                            s_rem  = remain - (int)(cum - hist[bb]);
                            break;
                        }
                    }
                }
                __syncthreads();
                if (p == 1) pref = (pref << 12) | s_pref;
                else        pref = (pref << 8)  | s_pref;
                remain = s_rem;
                __syncthreads();
            }
            th[b] = __uint_as_float((pref & 0x80000000u) ? (pref ^ 0x80000000u) : ~pref);
        }
    }

    // ---- build phase: U1 := clip(sr + dsp,0) - dsm; sparse sums ----
    const float thp = th[0], thm = th[1];
    float* u1 = U1 + (size_t)row * VSZ;
    const float* u2 = U2 + (size_t)row * VSZ;
    const float* s  = sr + (size_t)row * VSZ;
    float sp = 0.f, sm = 0.f;
    for (int j = t; j < VSZ / 2; j += TKT) {
        const float2 up = *(const float2*)(u1 + 2 * j);
        const float2 um = *(const float2*)(u2 + 2 * j);
        const float2 ss = *(const float2*)(s  + 2 * j);
        const float dp0 = (up.x >= thp) ? softplus_f(up.x) : 0.f;
        const float dp1 = (up.y >= thp) ? softplus_f(up.y) : 0.f;
        const float dm0 = (um.x >= thm) ? softplus_f(um.x) : 0.f;
        const float dm1 = (um.y >= thm) ? softplus_f(um.y) : 0.f;
        sp += dp0 + dp1; sm += dm0 + dm1;
        float2 o;
        o.x = fmaxf(ss.x + dp0, 0.f) - dm0;
        o.y = fmaxf(ss.y + dp1, 0.f) - dm1;
        *(float2*)(u1 + 2 * j) = o;
    }
    __syncthreads();
    fred[t] = sp; __syncthreads();
    for (int o = TKT / 2; o > 0; o >>= 1) { if (t < o) fred[t] += fred[t + o]; __syncthreads(); }
    if (t == 0) sparse_p[row] = fred[0];
    __syncthreads();
    fred[t] = sm; __syncthreads();
    for (int o = TKT / 2; o > 0; o >>= 1) { if (t < o) fred[t] += fred[t + o]; __syncthreads(); }
    if (t == 0) sparse_m[row] = fred[0];
}

__global__ __launch_bounds__(256) void rownorm(
    const float* __restrict__ X, float* __restrict__ Y, int dbl)
{
    __shared__ float red[256];
    const int row = blockIdx.x, t = threadIdx.x;
    const float* x = X + (size_t)row * DIM;
    float* y = Y + (size_t)row * DIM;
    float v0 = x[t], v1 = x[t + 256], v2 = x[t + 512];
    red[t] = v0 * v0 + v1 * v1 + v2 * v2; __syncthreads();
    for (int o = 128; o > 0; o >>= 1) { if (t < o) red[t] += red[t + o]; __syncthreads(); }
    const float nrm = sqrtf(red[0]) + EPSN;
    v0 /= nrm; v1 /= nrm; v2 /= nrm;
    if (dbl) {
        __syncthreads();
        red[t] = v0 * v0 + v1 * v1 + v2 * v2; __syncthreads();
        for (int o = 128; o > 0; o >>= 1) { if (t < o) red[t] += red[t + o]; __syncthreads(); }
        const float n2 = sqrtf(red[0]) + EPSN;
        v0 /= n2; v1 /= n2; v2 /= n2;
    }
    y[t] = v0; y[t + 256] = v1; y[t + 512] = v2;
}

__global__ __launch_bounds__(256) void pos_dot(
    const float* __restrict__ zq, const float* __restrict__ zp,
    float* __restrict__ posL)
{
    __shared__ float red[256];
    const int row = blockIdx.x, t = threadIdx.x;
    const float* a = zq + (size_t)row * DIM;
    const float* b = zp + (size_t)row * DIM;
    red[t] = a[t] * b[t] + a[t + 256] * b[t + 256] + a[t + 512] * b[t + 512];
    __syncthreads();
    for (int o = 128; o > 0; o >>= 1) { if (t < o) red[t] += red[t + o]; __syncthreads(); }
    if (t == 0) posL[row] = red[0] / TEMPC;
}

// NegL holds raw dot products; scale by 1/TEMP here.
__global__ __launch_bounds__(256) void lse_loss(
    const float* __restrict__ negL, const float* __restrict__ posL,
    float* __restrict__ rowL)
{
    __shared__ float red[256];
    const int row = blockIdx.x, t = threadIdx.x;
    const float* nl = negL + (size_t)row * MNEG;
    const float p = posL[row];
    float lmax = (t == 0) ? p : -INFINITY;
    for (int j = t; j < MNEG; j += 256) lmax = fmaxf(lmax, nl[j] * INVT);
    red[t] = lmax; __syncthreads();
    for (int o = 128; o > 0; o >>= 1) { if (t < o) red[t] = fmaxf(red[t], red[t + o]); __syncthreads(); }
    const float mx = red[0];
    __syncthreads();
    float lsum = (t == 0) ? expf(p - mx) : 0.f;
    for (int j = t; j < MNEG; j += 256) lsum += expf(nl[j] * INVT - mx);
    red[t] = lsum; __syncthreads();
    for (int o = 128; o > 0; o >>= 1) { if (t < o) red[t] += red[t + o]; __syncthreads(); }
    if (t == 0) rowL[row] = mx + logf(red[0]) - p;
}

__global__ __launch_bounds__(256) void rec_row(
    const float* __restrict__ zhat, const float* __restrict__ zrn,
    float* __restrict__ part)
{
    __shared__ float red[256];
    const int row = blockIdx.x, t = threadIdx.x;
    const float* a = zhat + (size_t)row * DIM;
    const float* b = zrn + (size_t)row * DIM;
    const float d0 = a[t] - b[t], d1 = a[t + 256] - b[t + 256], d2 = a[t + 512] - b[t + 512];
    red[t] = d0 * d0 + d1 * d1 + d2 * d2;
    __syncthreads();
    for (int o = 128; o > 0; o >>= 1) { if (t < o) red[t] += red[t + o]; __syncthreads(); }
    if (t == 0) part[row] = red[0];
}

__global__ __launch_bounds__(256) void final_combine(
    const float* __restrict__ rowL, const float* __restrict__ recP,
    const float* __restrict__ spP, const float* __restrict__ spM,
    float* __restrict__ out)
{
    __shared__ float red[256];
    const int t = threadIdx.x;
    red[t] = rowL[t]; __syncthreads();
    for (int o = 128; o > 0; o >>= 1) { if (t < o) red[t] += red[t + o]; __syncthreads(); }
    const float retr = red[0] / 256.0f;
    __syncthreads();
    red[t] = recP[t]; __syncthreads();
    for (int o = 128; o > 0; o >>= 1) { if (t < o) red[t] += red[t + o]; __syncthreads(); }
    const float rec = red[0] / (float)(BATCH * DIM);
    __syncthreads();
    red[t] = spP[t] + spM[t]; __syncthreads();
    for (int o = 128; o > 0; o >>= 1) { if (t < o) red[t] += red[t + o]; __syncthreads(); }
    const float sparse = red[0] / 256.0f;
    if (t == 0) out[0] = retr + 1.0f * rec + 1e-4f * sparse;
}

extern "C" void kernel_launch(void* const* d_in, const int* in_sizes, int n_in,
                              void* d_out, int out_size, void* d_ws, size_t ws_size,
                              hipStream_t stream)
{
    const float* ht   = (const float*)d_in[0];
    const float* sr   = (const float*)d_in[1];
    const float* zpos = (const float*)d_in[2];
    const float* zneg = (const float*)d_in[3];
    const float* zr   = (const float*)d_in[4];
    const float* W1p  = (const float*)d_in[5];
    const float* b1p  = (const float*)d_in[6];
    const float* W2p  = (const float*)d_in[7];
    const float* b2p  = (const float*)d_in[8];
    const float* W1m  = (const float*)d_in[9];
    const float* b1m  = (const float*)d_in[10];
    const float* W2m  = (const float*)d_in[11];
    const float* b2m  = (const float*)d_in[12];
    const float* Wdec = (const float*)d_in[13];
    float* out = (float*)d_out;

    // workspace layout (bytes) — R8/R17 layout
    char* ws = (char*)d_ws;
    float* U1   = (float*)(ws + 0);            // 31,254,528 (u_p raw -> sq)
    float* U2   = (float*)(ws + 31254528);     // 31,254,528 (u_m raw; dead after topk_build ->
                                               //   reused as decode branch-m partials)
    float* P    = (float*)(ws + 62509056);     // 33,554,432 partial arena (serial reuse)
    float* P1g  = (float*)(ws + 62509056 + 16777216);  // gemm1 branch-m partials
    float* Hp   = (float*)(ws + 96063488);     //      524,288
    float* Hm   = (float*)(ws + 96587776);     //      524,288
    float* Y1   = (float*)(ws + 97112064);     //      786,432
    float* Y2   = (float*)(ws + 97898496);     //      786,432
    float* Zn   = (float*)(ws + 98684928);     //   12,582,912
    float* Zp   = (float*)(ws + 111267840);    //      786,432
    float* Zrn  = (float*)(ws + 112054272);    //      786,432
    float* NegL = (float*)(ws + 112840704);    //    4,194,304
    float* tP   = (float*)(ws + 117035008);    // small vectors (256 floats each)
    float* tM   = tP + 256;
    float* spP  = tP + 512;
    float* spM  = tP + 768;
    float* posL = tP + 1024;
    float* rowL = tP + 1280;
    float* recP = tP + 1536;
    (void)in_sizes; (void)n_in; (void)out_size; (void)ws_size; (void)tM; (void)tP;

    const dim3 blk(256);

    // ---- GEMM1 dual (ht@W1p | ht@W1m), split-K 32 each, grid 512 blocks
    gemm32t<0,0,0, VSZ, BOT, BOT, VSZ, 32, 2,4,64><<<dim3(2,4,64), blk, 0, stream>>>(
        ht, ht, W1p, W1m, P, P1g, nullptr, nullptr);
    reduce_bias_gelu2<<<dim3(512,2), blk, 0, stream>>>(
        P, P1g, b1p, b1m, Hp, Hm, BATCH*BOT, BOT, 32);

    // ---- GEMM2 dual (Hp@W2p | Hm@W2m), raw acc+bias epilogue, grid 956
    gemm32t<0,1,1, BOT, VSZ, VSZ, BOT, 1, 2,239,2><<<dim3(2,239,2), blk, 0, stream>>>(
        Hp, Hm, W2p, W2m, U1, U2, b2p, b2m);

    // ---- fused top-K (collect-select) + sq build + sparse sums
    topk_build<<<dim3(256), dim3(TKT), 0, stream>>>(U1, U2, sr, spP, spM);

    // ---- decode dual (sq@Wdec | sr@Wdec), split-K 32, grid 768
    //      branch-p partials -> P, branch-m partials -> dead U2 region
    gemm32t<0,0,0, VSZ, DIM, DIM, VSZ, 32, 2,6,64><<<dim3(2,6,64), blk, 0, stream>>>(
        U1, sr, Wdec, Wdec, P, U2, nullptr, nullptr);
    reduce_sum_parts<<<dim3(768), blk, 0, stream>>>(P,  Y1, BATCH*DIM, 32);
    reduce_sum_parts<<<dim3(768), blk, 0, stream>>>(U2, Y2, BATCH*DIM, 32);

    // ---- normalizations
    rownorm<<<dim3(256),  blk, 0, stream>>>(Y1, Y1, 1);   // zq (double norm)
    rownorm<<<dim3(256),  blk, 0, stream>>>(Y2, Y2, 0);   // zhat_r
    rownorm<<<dim3(4096), blk, 0, stream>>>(zneg, Zn, 0);
    rownorm<<<dim3(256),  blk, 0, stream>>>(zpos, Zp, 0);
    rownorm<<<dim3(256),  blk, 0, stream>>>(zr,   Zrn, 0);

    // ---- retrieval loss
    pos_dot<<<dim3(256), blk, 0, stream>>>(Y1, Zp, posL);
    gemm32t<1,0,0, DIM, DIM, MNEG, DIM, 4, 2,32,4><<<dim3(2,32,4), blk, 0, stream>>>(
        Y1, Y1, Zn, Zn, P, P, nullptr, nullptr);
    reduce_sum_parts<<<dim3(4096), blk, 0, stream>>>(P, NegL, BATCH*MNEG, 4);
    lse_loss<<<dim3(256), blk, 0, stream>>>(NegL, posL, rowL);

    // ---- reconstruction loss
    rec_row<<<dim3(256), blk, 0, stream>>>(Y2, Zrn, recP);

    // ---- combine
    final_combine<<<dim3(1), blk, 0, stream>>>(rowL, recP, spP, spM, out);
}

// Round 23
// 391.309 us; speedup vs baseline: 1.2363x; 1.2363x over previous
//
#include <hip/hip_runtime.h>
#include <math.h>

#define VSZ   30522
#define DIM   768
#define KDELT 768
#define BOT   512
#define BATCH 256
#define MNEG  4096
#define EPSN  1e-6f
#define TEMPC 0.05f
#define INVT  20.0f
#define TKT   1024
#define CCAP  2048

typedef _Float16 f16;
typedef _Float16 f16x8 __attribute__((ext_vector_type(8)));
typedef _Float16 f16x2 __attribute__((ext_vector_type(2)));
typedef float    f32x4 __attribute__((ext_vector_type(4)));

static __device__ __forceinline__ float gelu_exact(float x){
    return 0.5f * x * (1.0f + erff(x * 0.70710678118654752440f));
}
static __device__ __forceinline__ float softplus_f(float x){
    return fmaxf(x, 0.0f) + log1pf(expf(-fabsf(x)));
}
static __device__ __forceinline__ f16x2 pkh(float a, float b){
    return __builtin_bit_cast(f16x2, __builtin_amdgcn_cvt_pkrtz(a, b));
}
// order-preserving map float -> uint (handles negatives)
static __device__ __forceinline__ unsigned int fkey(float f){
    const unsigned int u = __float_as_uint(f);
    return u ^ (((unsigned int)((int)u >> 31)) | 0x80000000u);
}

// ---------------------------------------------------------------------------
// fp32-in / fp16-MFMA GEMM, 128x128 tile + XCD swizzle — EXACT R17 kernel.
// R22's minimal 2-deep prefetch regressed (VGPR 96, 164us, 0.8 TB/s) —
// second independent confirmation that source-level pipeline depth >1 is
// counterproductive here (compiler serializes staging dataflow across the
// barrier). 1-deep prefetch restored; this is the best-known configuration.
// ---------------------------------------------------------------------------
template<int BSRC, int NG, int EPI, int LDA, int LDB, int N, int K, int NSPLIT,
         int GX, int GY, int GZ>
__global__ __launch_bounds__(256, 2) void gemm32t(
    const float* __restrict__ A0, const float* __restrict__ A1,
    const float* __restrict__ B0, const float* __restrict__ B1,
    float* __restrict__ C0, float* __restrict__ C1,
    const float* __restrict__ bias0, const float* __restrict__ bias1)
{
    constexpr int MN = BATCH * N;
    __shared__ f16 Al[128][40];
    __shared__ f16 Bl[128][40];
    const int t  = threadIdx.x;

    // ---- XCD-aware bijective remap (hw dispatch slot -> work id) ----
    const int flat = blockIdx.x + GX * (blockIdx.y + GY * blockIdx.z);
    constexpr int NWG = GX * GY * GZ;
    constexpr int q8 = NWG / 8, r8 = NWG % 8;
    const int xcd = flat & 7;
    const int sub = flat >> 3;
    const int wg  = (xcd < r8) ? (xcd * (q8 + 1) + sub)
                               : (r8 * (q8 + 1) + (xcd - r8) * q8 + sub);
    const int bx = wg % GX;
    const int by = (wg / GX) % GY;
    const int bz = wg / (GX * GY);

    const int m0 = bx * 128;
    const int n0 = by * 128;
    const int br = bz / NSPLIT;
    const int s  = bz % NSPLIT;
    const float* __restrict__ A = br ? A1 : A0;
    const float* __restrict__ B = br ? B1 : B0;
    float* __restrict__ C       = br ? C1 : C0;
    const float* __restrict__ bias = br ? bias1 : bias0;

    constexpr int kchunk = ((K + NSPLIT * 32 - 1) / (NSPLIT * 32)) * 32;
    const int kb = s * kchunk;
    const int ke = min(K, kb + kchunk);

    const int ar4 = t >> 2;          // staging row 0..63 (two passes)
    const int kq  = (t & 3) * 8;     // k-octet base 0,8,16,24
    const int bn  = t & 127;         // B transpose staging n
    const int bk2 = (t >> 7) * 16;   // B staging k-half base 0/16

    const int lane = t & 63, w = t >> 6;
    const int wr = (w >> 1) * 64, wc = (w & 1) * 64;
    const int fr = lane & 15, kg = (lane >> 4) * 8;

    f32x4 acc[4][4] = {};

    float4 ra[2][2];
    float  rb[16];
    float4 rb2[2][2];

    union U8 { f16x8 v; f16x2 h[4]; };

    auto loadA = [&](int k0c, int krem) {
        #pragma unroll
        for (int p = 0; p < 2; p++) {
            const float* ap = A + (size_t)(m0 + p * 64 + ar4) * LDA + k0c + kq;
            if (krem == 32) {
                ra[p][0] = *(const float4*)ap;
                ra[p][1] = *(const float4*)(ap + 4);
            } else {
                float tm[8];
                #pragma unroll
                for (int i = 0; i < 8; i++) tm[i] = (kq + i < krem) ? ap[i] : 0.f;
                ra[p][0] = make_float4(tm[0], tm[1], tm[2], tm[3]);
                ra[p][1] = make_float4(tm[4], tm[5], tm[6], tm[7]);
            }
        }
    };
    auto loadB = [&](int k0c, int krem) {
        if (BSRC == 0) {
            const bool nok = (!NG) || (n0 + bn < N);
            if (krem == 32) {
                #pragma unroll
                for (int p = 0; p < 16; p++)
                    rb[p] = nok ? B[(size_t)(k0c + bk2 + p) * LDB + n0 + bn] : 0.f;
            } else {
                #pragma unroll
                for (int p = 0; p < 16; p++) {
                    const int kk = bk2 + p;
                    rb[p] = (kk < krem && nok) ? B[(size_t)(k0c + kk) * LDB + n0 + bn] : 0.f;
                }
            }
        } else {
            #pragma unroll
            for (int p = 0; p < 2; p++) {
                const float* bp = B + (size_t)(n0 + p * 64 + ar4) * LDB + k0c + kq;
                if (krem == 32) {
                    rb2[p][0] = *(const float4*)bp;
                    rb2[p][1] = *(const float4*)(bp + 4);
                } else {
                    float tm[8];
                    #pragma unroll
                    for (int i = 0; i < 8; i++) tm[i] = (kq + i < krem) ? bp[i] : 0.f;
                    rb2[p][0] = make_float4(tm[0], tm[1], tm[2], tm[3]);
                    rb2[p][1] = make_float4(tm[4], tm[5], tm[6], tm[7]);
                }
            }
        }
    };
    auto storeA = [&]() {
        #pragma unroll
        for (int p = 0; p < 2; p++) {
            U8 u;
            u.h[0] = pkh(ra[p][0].x, ra[p][0].y);
            u.h[1] = pkh(ra[p][0].z, ra[p][0].w);
            u.h[2] = pkh(ra[p][1].x, ra[p][1].y);
            u.h[3] = pkh(ra[p][1].z, ra[p][1].w);
            *(f16x8*)&Al[p * 64 + ar4][kq] = u.v;
        }
    };
    auto storeB = [&]() {
        if (BSRC == 0) {
            U8 u0, u1;
            u0.h[0] = pkh(rb[0],  rb[1]);
            u0.h[1] = pkh(rb[2],  rb[3]);
            u0.h[2] = pkh(rb[4],  rb[5]);
            u0.h[3] = pkh(rb[6],  rb[7]);
            u1.h[0] = pkh(rb[8],  rb[9]);
            u1.h[1] = pkh(rb[10], rb[11]);
            u1.h[2] = pkh(rb[12], rb[13]);
            u1.h[3] = pkh(rb[14], rb[15]);
            *(f16x8*)&Bl[bn][bk2]     = u0.v;
            *(f16x8*)&Bl[bn][bk2 + 8] = u1.v;
        } else {
            #pragma unroll
            for (int p = 0; p < 2; p++) {
                U8 u;
                u.h[0] = pkh(rb2[p][0].x, rb2[p][0].y);
                u.h[1] = pkh(rb2[p][0].z, rb2[p][0].w);
                u.h[2] = pkh(rb2[p][1].x, rb2[p][1].y);
                u.h[3] = pkh(rb2[p][1].z, rb2[p][1].w);
                *(f16x8*)&Bl[p * 64 + ar4][kq] = u.v;
            }
        }
    };

    int k0 = kb;
    {
        const int kr = min(32, ke - k0);
        loadA(k0, kr); loadB(k0, kr);
    }
    while (k0 < ke) {
        storeA(); storeB();
        __syncthreads();
        const int k1 = k0 + 32;
        if (k1 < ke) {                       // prefetch next tile into regs
            const int kr = min(32, ke - k1);
            loadA(k1, kr); loadB(k1, kr);
        }
        f16x8 af[4], bf[4];
        #pragma unroll
        for (int m = 0; m < 4; m++) af[m] = *(const f16x8*)&Al[wr + m * 16 + fr][kg];
        #pragma unroll
        for (int n = 0; n < 4; n++) bf[n] = *(const f16x8*)&Bl[wc + n * 16 + fr][kg];
        #pragma unroll
        for (int m = 0; m < 4; m++)
            #pragma unroll
            for (int n = 0; n < 4; n++)
                acc[m][n] = __builtin_amdgcn_mfma_f32_16x16x32_f16(af[m], bf[n], acc[m][n], 0, 0, 0);
        __syncthreads();
        k0 = k1;
    }

    float* Cp = (EPI == 0) ? (C + (size_t)s * MN) : C;
    #pragma unroll
    for (int m = 0; m < 4; m++) {
        #pragma unroll
        for (int n = 0; n < 4; n++) {
            #pragma unroll
            for (int j = 0; j < 4; j++) {
                const int row = m0 + wr + m * 16 + (lane >> 4) * 4 + j;
                const int col = n0 + wc + n * 16 + fr;
                if (NG && col >= N) continue;
                if (EPI == 0) Cp[(size_t)row * N + col] = acc[m][n][j];
                else          Cp[(size_t)row * N + col] = acc[m][n][j] + bias[col];
            }
        }
    }
}

// dual-branch split-K reduce + bias + exact GELU
__global__ __launch_bounds__(256) void reduce_bias_gelu2(
    const float* __restrict__ P0, const float* __restrict__ P1,
    const float* __restrict__ bias0, const float* __restrict__ bias1,
    float* __restrict__ H0, float* __restrict__ H1,
    int MN, int N, int nsplit)
{
    const int idx = blockIdx.x * 256 + threadIdx.x;
    if (idx >= MN) return;
    const int n = idx % N;
    const float* P = blockIdx.y ? P1 : P0;
    const float* bias = blockIdx.y ? bias1 : bias0;
    float* H = blockIdx.y ? H1 : H0;
    float s = 0.f;
    for (int k = 0; k < nsplit; k++) s += P[(size_t)k * MN + idx];
    H[idx] = gelu_exact(s + bias[n]);
}

__global__ __launch_bounds__(256) void reduce_sum_parts(
    const float* __restrict__ P, float* __restrict__ Y, int MN, int nsplit)
{
    const int idx = blockIdx.x * 256 + threadIdx.x;
    if (idx >= MN) return;
    float s = 0.f;
    for (int k = 0; k < nsplit; k++) s += P[(size_t)k * MN + idx];
    Y[idx] = s;
}

// ---------------------------------------------------------------------------
// FUSED per-row kernel (R20 collect-select): pass A = 12-bit histogram +
// suffix scan -> boundary bin & rank; pass B = collect bin elements to LDS,
// value-count select (order-independent, exact); fallback full radix if
// bin > CCAP. Then build sq in place + sparse sums.
// ---------------------------------------------------------------------------
__global__ __launch_bounds__(TKT) void topk_build(
    float* __restrict__ U1, const float* __restrict__ U2,
    const float* __restrict__ sr,
    float* __restrict__ sparse_p, float* __restrict__ sparse_m)
{
    __shared__ unsigned int hist[4096];
    __shared__ unsigned int scan[TKT];
    __shared__ unsigned int cand[CCAP];
    __shared__ unsigned int s_pref;
    __shared__ int s_rem;
    __shared__ unsigned int s_cnt;
    __shared__ unsigned int s_thr;
    const int row = blockIdx.x, t = threadIdx.x;
    float* fred = (float*)hist;              // build-phase reduction (aliases hist)

    float th[2];
    #pragma unroll
    for (int b = 0; b < 2; b++) {
        const float* u = (b ? U2 : U1) + (size_t)row * VSZ;

        // ---- pass A: 12-bit histogram ----
        for (int i = t; i < 4096; i += TKT) hist[i] = 0;
        __syncthreads();
        for (int j = t; j < VSZ / 2; j += TKT) {
            const float2 x = *(const float2*)(u + 2 * j);
            atomicAdd(&hist[fkey(x.x) >> 20], 1u);
            atomicAdd(&hist[fkey(x.y) >> 20], 1u);
        }
        __syncthreads();
        // suffix scan: thread t owns bins [4t, 4t+4)
        unsigned int loc = hist[4 * t] + hist[4 * t + 1] + hist[4 * t + 2] + hist[4 * t + 3];
        scan[t] = loc;
        __syncthreads();
        for (int o = 1; o < TKT; o <<= 1) {
            const unsigned int v = (t + o < TKT) ? scan[t + o] : 0u;
            __syncthreads();
            scan[t] += v;
            __syncthreads();
        }
        const unsigned int above = (t + 1 < TKT) ? scan[t + 1] : 0u;
        if (scan[t] >= (unsigned int)KDELT && above < (unsigned int)KDELT) {
            unsigned int cum = above;
            #pragma unroll
            for (int bi = 3; bi >= 0; bi--) {
                const int bb = 4 * t + bi;
                cum += hist[bb];
                if (cum >= (unsigned int)KDELT) {
                    s_pref = (unsigned int)bb;
                    s_rem  = KDELT - (int)(cum - hist[bb]);
                    break;
                }
            }
        }
        __syncthreads();
        const unsigned int bin = s_pref;
        const int r = s_rem;
        const unsigned int bincnt = hist[bin];

        if (bincnt <= CCAP) {
            // ---- pass B: collect boundary-bin elements, value-count select
            if (t == 0) s_cnt = 0;
            __syncthreads();
            for (int j = t; j < VSZ / 2; j += TKT) {
                const float2 x = *(const float2*)(u + 2 * j);
                const unsigned int k0 = fkey(x.x);
                const unsigned int k1 = fkey(x.y);
                if ((k0 >> 20) == bin) cand[atomicAdd(&s_cnt, 1u)] = k0;
                if ((k1 >> 20) == bin) cand[atomicAdd(&s_cnt, 1u)] = k1;
            }
            __syncthreads();
            const int cnt = (int)s_cnt;
            for (int i = t; i < cnt; i += TKT) {
                const unsigned int ki = cand[i];
                int greater = 0, eq = 0;
                for (int j2 = 0; j2 < cnt; j2++) {
                    const unsigned int kj = cand[j2];
                    greater += (kj > ki);
                    eq      += (kj == ki);
                }
                if (greater < r && r <= greater + eq) s_thr = ki;
            }
            __syncthreads();
            const unsigned int pk = s_thr;
            th[b] = __uint_as_float((pk & 0x80000000u) ? (pk ^ 0x80000000u) : ~pk);
            __syncthreads();
        } else {
            // ---- fallback: original 12-bit then 8-bit refinement passes
            unsigned int pref = bin;
            int remain = r;
            #pragma unroll
            for (int p = 1; p < 3; p++) {
                for (int i = t; i < 4096; i += TKT) hist[i] = 0;
                __syncthreads();
                for (int j = t; j < VSZ / 2; j += TKT) {
                    const float2 x = *(const float2*)(u + 2 * j);
                    const unsigned int k0 = fkey(x.x);
                    const unsigned int k1 = fkey(x.y);
                    if (p == 1) {
                        if ((k0 >> 20) == pref) atomicAdd(&hist[(k0 >> 8) & 0xFFFu], 1u);
                        if ((k1 >> 20) == pref) atomicAdd(&hist[(k1 >> 8) & 0xFFFu], 1u);
                    } else {
                        if ((k0 >> 8) == pref) atomicAdd(&hist[k0 & 0xFFu], 1u);
                        if ((k1 >> 8) == pref) atomicAdd(&hist[k1 & 0xFFu], 1u);
                    }
                }
                __syncthreads();
                unsigned int loc2 = hist[4 * t] + hist[4 * t + 1] + hist[4 * t + 2] + hist[4 * t + 3];
                scan[t] = loc2;
                __syncthreads();
                for (int o = 1; o < TKT; o <<= 1) {
                    const unsigned int v = (t + o < TKT) ? scan[t + o] : 0u;
                    __syncthreads();
                    scan[t] += v;
                    __syncthreads();
                }
                const unsigned int abv = (t + 1 < TKT) ? scan[t + 1] : 0u;
                if (scan[t] >= (unsigned int)remain && abv < (unsigned int)remain) {
                    unsigned int cum = abv;
                    #pragma unroll
                    for (int bi = 3; bi >= 0; bi--) {
                        const int bb = 4 * t + bi;
                        cum += hist[bb];
                        if (cum >= (unsigned int)remain) {
                            s_pref = (unsigned int)bb;
                            s_rem  = remain - (int)(cum - hist[bb]);
                            break;
                        }
                    }
                }
                __syncthreads();
                if (p == 1) pref = (pref << 12) | s_pref;
                else        pref = (pref << 8)  | s_pref;
                remain = s_rem;
                __syncthreads();
            }
            th[b] = __uint_as_float((pref & 0x80000000u) ? (pref ^ 0x80000000u) : ~pref);
        }
    }

    // ---- build phase: U1 := clip(sr + dsp,0) - dsm; sparse sums ----
    const float thp = th[0], thm = th[1];
    float* u1 = U1 + (size_t)row * VSZ;
    const float* u2 = U2 + (size_t)row * VSZ;
    const float* s  = sr + (size_t)row * VSZ;
    float sp = 0.f, sm = 0.f;
    for (int j = t; j < VSZ / 2; j += TKT) {
        const float2 up = *(const float2*)(u1 + 2 * j);
        const float2 um = *(const float2*)(u2 + 2 * j);
        const float2 ss = *(const float2*)(s  + 2 * j);
        const float dp0 = (up.x >= thp) ? softplus_f(up.x) : 0.f;
        const float dp1 = (up.y >= thp) ? softplus_f(up.y) : 0.f;
        const float dm0 = (um.x >= thm) ? softplus_f(um.x) : 0.f;
        const float dm1 = (um.y >= thm) ? softplus_f(um.y) : 0.f;
        sp += dp0 + dp1; sm += dm0 + dm1;
        float2 o;
        o.x = fmaxf(ss.x + dp0, 0.f) - dm0;
        o.y = fmaxf(ss.y + dp1, 0.f) - dm1;
        *(float2*)(u1 + 2 * j) = o;
    }
    __syncthreads();
    fred[t] = sp; __syncthreads();
    for (int o = TKT / 2; o > 0; o >>= 1) { if (t < o) fred[t] += fred[t + o]; __syncthreads(); }
    if (t == 0) sparse_p[row] = fred[0];
    __syncthreads();
    fred[t] = sm; __syncthreads();
    for (int o = TKT / 2; o > 0; o >>= 1) { if (t < o) fred[t] += fred[t + o]; __syncthreads(); }
    if (t == 0) sparse_m[row] = fred[0];
}

__global__ __launch_bounds__(256) void rownorm(
    const float* __restrict__ X, float* __restrict__ Y, int dbl)
{
    __shared__ float red[256];
    const int row = blockIdx.x, t = threadIdx.x;
    const float* x = X + (size_t)row * DIM;
    float* y = Y + (size_t)row * DIM;
    float v0 = x[t], v1 = x[t + 256], v2 = x[t + 512];
    red[t] = v0 * v0 + v1 * v1 + v2 * v2; __syncthreads();
    for (int o = 128; o > 0; o >>= 1) { if (t < o) red[t] += red[t + o]; __syncthreads(); }
    const float nrm = sqrtf(red[0]) + EPSN;
    v0 /= nrm; v1 /= nrm; v2 /= nrm;
    if (dbl) {
        __syncthreads();
        red[t] = v0 * v0 + v1 * v1 + v2 * v2; __syncthreads();
        for (int o = 128; o > 0; o >>= 1) { if (t < o) red[t] += red[t + o]; __syncthreads(); }
        const float n2 = sqrtf(red[0]) + EPSN;
        v0 /= n2; v1 /= n2; v2 /= n2;
    }
    y[t] = v0; y[t + 256] = v1; y[t + 512] = v2;
}

__global__ __launch_bounds__(256) void pos_dot(
    const float* __restrict__ zq, const float* __restrict__ zp,
    float* __restrict__ posL)
{
    __shared__ float red[256];
    const int row = blockIdx.x, t = threadIdx.x;
    const float* a = zq + (size_t)row * DIM;
    const float* b = zp + (size_t)row * DIM;
    red[t] = a[t] * b[t] + a[t + 256] * b[t + 256] + a[t + 512] * b[t + 512];
    __syncthreads();
    for (int o = 128; o > 0; o >>= 1) { if (t < o) red[t] += red[t + o]; __syncthreads(); }
    if (t == 0) posL[row] = red[0] / TEMPC;
}

// NegL holds raw dot products; scale by 1/TEMP here.
__global__ __launch_bounds__(256) void lse_loss(
    const float* __restrict__ negL, const float* __restrict__ posL,
    float* __restrict__ rowL)
{
    __shared__ float red[256];
    const int row = blockIdx.x, t = threadIdx.x;
    const float* nl = negL + (size_t)row * MNEG;
    const float p = posL[row];
    float lmax = (t == 0) ? p : -INFINITY;
    for (int j = t; j < MNEG; j += 256) lmax = fmaxf(lmax, nl[j] * INVT);
    red[t] = lmax; __syncthreads();
    for (int o = 128; o > 0; o >>= 1) { if (t < o) red[t] = fmaxf(red[t], red[t + o]); __syncthreads(); }
    const float mx = red[0];
    __syncthreads();
    float lsum = (t == 0) ? expf(p - mx) : 0.f;
    for (int j = t; j < MNEG; j += 256) lsum += expf(nl[j] * INVT - mx);
    red[t] = lsum; __syncthreads();
    for (int o = 128; o > 0; o >>= 1) { if (t < o) red[t] += red[t + o]; __syncthreads(); }
    if (t == 0) rowL[row] = mx + logf(red[0]) - p;
}

__global__ __launch_bounds__(256) void rec_row(
    const float* __restrict__ zhat, const float* __restrict__ zrn,
    float* __restrict__ part)
{
    __shared__ float red[256];
    const int row = blockIdx.x, t = threadIdx.x;
    const float* a = zhat + (size_t)row * DIM;
    const float* b = zrn + (size_t)row * DIM;
    const float d0 = a[t] - b[t], d1 = a[t + 256] - b[t + 256], d2 = a[t + 512] - b[t + 512];
    red[t] = d0 * d0 + d1 * d1 + d2 * d2;
    __syncthreads();
    for (int o = 128; o > 0; o >>= 1) { if (t < o) red[t] += red[t + o]; __syncthreads(); }
    if (t == 0) part[row] = red[0];
}

__global__ __launch_bounds__(256) void final_combine(
    const float* __restrict__ rowL, const float* __restrict__ recP,
    const float* __restrict__ spP, const float* __restrict__ spM,
    float* __restrict__ out)
{
    __shared__ float red[256];
    const int t = threadIdx.x;
    red[t] = rowL[t]; __syncthreads();
    for (int o = 128; o > 0; o >>= 1) { if (t < o) red[t] += red[t + o]; __syncthreads(); }
    const float retr = red[0] / 256.0f;
    __syncthreads();
    red[t] = recP[t]; __syncthreads();
    for (int o = 128; o > 0; o >>= 1) { if (t < o) red[t] += red[t + o]; __syncthreads(); }
    const float rec = red[0] / (float)(BATCH * DIM);
    __syncthreads();
    red[t] = spP[t] + spM[t]; __syncthreads();
    for (int o = 128; o > 0; o >>= 1) { if (t < o) red[t] += red[t + o]; __syncthreads(); }
    const float sparse = red[0] / 256.0f;
    if (t == 0) out[0] = retr + 1.0f * rec + 1e-4f * sparse;
}

extern "C" void kernel_launch(void* const* d_in, const int* in_sizes, int n_in,
                              void* d_out, int out_size, void* d_ws, size_t ws_size,
                              hipStream_t stream)
{
    const float* ht   = (const float*)d_in[0];
    const float* sr   = (const float*)d_in[1];
    const float* zpos = (const float*)d_in[2];
    const float* zneg = (const float*)d_in[3];
    const float* zr   = (const float*)d_in[4];
    const float* W1p  = (const float*)d_in[5];
    const float* b1p  = (const float*)d_in[6];
    const float* W2p  = (const float*)d_in[7];
    const float* b2p  = (const float*)d_in[8];
    const float* W1m  = (const float*)d_in[9];
    const float* b1m  = (const float*)d_in[10];
    const float* W2m  = (const float*)d_in[11];
    const float* b2m  = (const float*)d_in[12];
    const float* Wdec = (const float*)d_in[13];
    float* out = (float*)d_out;

    // workspace layout (bytes) — R8/R17 layout
    char* ws = (char*)d_ws;
    float* U1   = (float*)(ws + 0);            // 31,254,528 (u_p raw -> sq)
    float* U2   = (float*)(ws + 31254528);     // 31,254,528 (u_m raw; dead after topk_build ->
                                               //   reused as decode branch-m partials)
    float* P    = (float*)(ws + 62509056);     // 33,554,432 partial arena (serial reuse)
    float* P1g  = (float*)(ws + 62509056 + 16777216);  // gemm1 branch-m partials
    float* Hp   = (float*)(ws + 96063488);     //      524,288
    float* Hm   = (float*)(ws + 96587776);     //      524,288
    float* Y1   = (float*)(ws + 97112064);     //      786,432
    float* Y2   = (float*)(ws + 97898496);     //      786,432
    float* Zn   = (float*)(ws + 98684928);     //   12,582,912
    float* Zp   = (float*)(ws + 111267840);    //      786,432
    float* Zrn  = (float*)(ws + 112054272);    //      786,432
    float* NegL = (float*)(ws + 112840704);    //    4,194,304
    float* tP   = (float*)(ws + 117035008);    // small vectors (256 floats each)
    float* tM   = tP + 256;
    float* spP  = tP + 512;
    float* spM  = tP + 768;
    float* posL = tP + 1024;
    float* rowL = tP + 1280;
    float* recP = tP + 1536;
    (void)in_sizes; (void)n_in; (void)out_size; (void)ws_size; (void)tM; (void)tP;

    const dim3 blk(256);

    // ---- GEMM1 dual (ht@W1p | ht@W1m), split-K 32 each, grid 512 blocks
    gemm32t<0,0,0, VSZ, BOT, BOT, VSZ, 32, 2,4,64><<<dim3(2,4,64), blk, 0, stream>>>(
        ht, ht, W1p, W1m, P, P1g, nullptr, nullptr);
    reduce_bias_gelu2<<<dim3(512,2), blk, 0, stream>>>(
        P, P1g, b1p, b1m, Hp, Hm, BATCH*BOT, BOT, 32);

    // ---- GEMM2 dual (Hp@W2p | Hm@W2m), raw acc+bias epilogue, grid 956
    gemm32t<0,1,1, BOT, VSZ, VSZ, BOT, 1, 2,239,2><<<dim3(2,239,2), blk, 0, stream>>>(
        Hp, Hm, W2p, W2m, U1, U2, b2p, b2m);

    // ---- fused top-K (collect-select) + sq build + sparse sums
    topk_build<<<dim3(256), dim3(TKT), 0, stream>>>(U1, U2, sr, spP, spM);

    // ---- decode dual (sq@Wdec | sr@Wdec), split-K 32, grid 768
    //      branch-p partials -> P, branch-m partials -> dead U2 region
    gemm32t<0,0,0, VSZ, DIM, DIM, VSZ, 32, 2,6,64><<<dim3(2,6,64), blk, 0, stream>>>(
        U1, sr, Wdec, Wdec, P, U2, nullptr, nullptr);
    reduce_sum_parts<<<dim3(768), blk, 0, stream>>>(P,  Y1, BATCH*DIM, 32);
    reduce_sum_parts<<<dim3(768), blk, 0, stream>>>(U2, Y2, BATCH*DIM, 32);

    // ---- normalizations
    rownorm<<<dim3(256),  blk, 0, stream>>>(Y1, Y1, 1);   // zq (double norm)
    rownorm<<<dim3(256),  blk, 0, stream>>>(Y2, Y2, 0);   // zhat_r
    rownorm<<<dim3(4096), blk, 0, stream>>>(zneg, Zn, 0);
    rownorm<<<dim3(256),  blk, 0, stream>>>(zpos, Zp, 0);
    rownorm<<<dim3(256),  blk, 0, stream>>>(zr,   Zrn, 0);

    // ---- retrieval loss
    pos_dot<<<dim3(256), blk, 0, stream>>>(Y1, Zp, posL);
    gemm32t<1,0,0, DIM, DIM, MNEG, DIM, 4, 2,32,4><<<dim3(2,32,4), blk, 0, stream>>>(
        Y1, Y1, Zn, Zn, P, P, nullptr, nullptr);
    reduce_sum_parts<<<dim3(4096), blk, 0, stream>>>(P, NegL, BATCH*MNEG, 4);
    lse_loss<<<dim3(256), blk, 0, stream>>>(NegL, posL, rowL);

    // ---- reconstruction loss
    rec_row<<<dim3(256), blk, 0, stream>>>(Y2, Zrn, recP);

    // ---- combine
    final_combine<<<dim3(1), blk, 0, stream>>>(rowL, recP, spP, spM, out);
}